// Round 6
// baseline (265.566 us; speedup 1.0000x reference)
//
#include <hip/hip_runtime.h>
#include <hip/hip_bf16.h>
#include <stdint.h>

#define BATCH 16384
#define MAXA 32
#define FEAT 768
#define HIDDEN 1024
#define RPB 16          // rows per block (= waves per block)
#define CHUNK 64        // staged columns per chunk (64 KB LDS)

// ---------------------------------------------------------------------------
// Prep 1: per-hidden-column max -> scale/invscale.
// ---------------------------------------------------------------------------
__global__ __launch_bounds__(256) void scale_k(const float* __restrict__ ftw,
                                               float* __restrict__ scale,
                                               float* __restrict__ invsc) {
  const int h = blockIdx.x;
  float a = 0.f;
#pragma unroll
  for (int p = 0; p < 3; ++p)
    a = fmaxf(a, fabsf(ftw[h * FEAT + p * 256 + threadIdx.x]));
#pragma unroll
  for (int off = 32; off > 0; off >>= 1)
    a = fmaxf(a, __shfl_xor(a, off, 64));
  __shared__ float red[4];
  if ((threadIdx.x & 63) == 0) red[threadIdx.x >> 6] = a;
  __syncthreads();
  if (threadIdx.x == 0) {
    float m = fmaxf(fmaxf(red[0], red[1]), fmaxf(red[2], red[3]));
    m = fmaxf(m, 1e-20f);
    scale[h] = m / 127.f;
    invsc[h] = 127.f / m;
  }
}

// ---------------------------------------------------------------------------
// Prep 2: quantize + transpose, LDS-tiled, coalesced reads + 16 B stores.
// wQ[f][h], 1 KB per feature column.
// ---------------------------------------------------------------------------
__global__ __launch_bounds__(256) void tilequant(const float* __restrict__ ftw,
                                                 const float* __restrict__ invsc,
                                                 uint8_t* __restrict__ wQ) {
  const int f0 = (blockIdx.x % (FEAT / 64)) * 64;
  const int h0 = (blockIdx.x / (FEAT / 64)) * 64;
  __shared__ uint8_t tile[64][80];
  __shared__ float inv[64];
  if (threadIdx.x < 64) inv[threadIdx.x] = invsc[h0 + threadIdx.x];
  __syncthreads();
  const int ff = threadIdx.x & 63;
  const int hb = threadIdx.x >> 6;
#pragma unroll
  for (int p = 0; p < 16; ++p) {
    int hh = p * 4 + hb;
    float w = ftw[(size_t)(h0 + hh) * FEAT + f0 + ff];
    int q = __float2int_rn(w * inv[hh]);
    tile[ff][hh] = (uint8_t)(q + 128);
  }
  __syncthreads();
  const int fs = threadIdx.x >> 2, part = threadIdx.x & 3;
  uint4 v = *(const uint4*)&tile[fs][part * 16];
  *(uint4*)(wQ + (size_t)(f0 + fs) * HIDDEN + h0 + part * 16) = v;
}

// packed u16 accumulate: plain u32 add == 2xu16 add (field max 32*255 = 8160).
__device__ __forceinline__ void acc16(uint32_t* acc, uint4 w) {
  acc[0] += __builtin_amdgcn_perm(0u, w.x, 0x0c010c00u);
  acc[1] += __builtin_amdgcn_perm(0u, w.x, 0x0c030c02u);
  acc[2] += __builtin_amdgcn_perm(0u, w.y, 0x0c010c00u);
  acc[3] += __builtin_amdgcn_perm(0u, w.y, 0x0c030c02u);
  acc[4] += __builtin_amdgcn_perm(0u, w.z, 0x0c010c00u);
  acc[5] += __builtin_amdgcn_perm(0u, w.z, 0x0c030c02u);
  acc[6] += __builtin_amdgcn_perm(0u, w.w, 0x0c010c00u);
  acc[7] += __builtin_amdgcn_perm(0u, w.w, 0x0c030c02u);
}

// 16 rows per 1024-thread block (1 wave per row). Block computes the union
// of its rows' features (bitmap -> sorted unique list, ~565 of 768), stages
// unique columns into LDS in 64-column chunks (prefetched into registers a
// chunk ahead), and every wave consumes its row's columns from LDS.
// L2 traffic: ~0.55x of the per-row gather version.
__global__ __launch_bounds__(1024, 8) void nn_fwd(
    const int* __restrict__ stm, const int* __restrict__ nstm,
    const uint8_t* __restrict__ wQ, const float* __restrict__ scale,
    const float* __restrict__ bias, const float* __restrict__ outw,
    const float* __restrict__ outb, float* __restrict__ out)
{
  const int tid  = threadIdx.x;
  const int lane = tid & 63;
  const int w    = tid >> 6;                  // wave id = local row
  const int row  = blockIdx.x * RPB + w;
  const int half = lane >> 5;                 // 0 = stm, 1 = nstm
  const int pos  = lane & 31;

  __shared__ uint32_t bitmap[24];             // 768-bit presence
  __shared__ uint32_t wordbase[24];           // exclusive popcount prefix
  __shared__ int      s_unique;
  __shared__ uint16_t ulist[FEAT];            // sorted unique feature ids
  __shared__ uint4    buf[CHUNK * 64];        // 64 KB column staging

  if (tid < 24) bitmap[tid] = 0u;
  __syncthreads();

  const int* __restrict__ src = half ? nstm : stm;
  int f = src[row * MAXA + pos];
  bool valid = f >= 0;
  // per-side dedupe: reference .at[].max() counts duplicates once
#pragma unroll
  for (int j = 0; j < 31; ++j) {
    int other = __shfl(f, (half << 5) | j, 64);
    if (j < pos && other == f) valid = false;
  }
  if (valid) atomicOr((unsigned int*)&bitmap[f >> 5], 1u << (f & 31));
  __syncthreads();

  // wave 0: prefix-sum word popcounts, emit sorted unique list
  if (tid < 64) {
    uint32_t wv = (tid < 24) ? bitmap[tid] : 0u;
    int cnt = __popc(wv);
    int inc = cnt;
#pragma unroll
    for (int off = 1; off < 32; off <<= 1) {
      int t = __shfl_up(inc, off, 64);
      if (lane >= off) inc += t;
    }
    if (tid < 24) {
      int excl = inc - cnt;
      wordbase[tid] = (uint32_t)excl;
      int r = excl; uint32_t wt = wv;
      while (wt) { int b = __builtin_ctz(wt); wt &= wt - 1u;
                   ulist[r++] = (uint16_t)(tid * 32 + b); }
      if (tid == 23) s_unique = inc;
    }
  }
  __syncthreads();

  const int su = s_unique;
  const int nchunks = (su + CHUNK - 1) / CHUNK;   // uniform across block

  // rank of this lane's feature in the sorted unique list
  int r_lane = 0x7FFFFFFF;
  if (valid)
    r_lane = (int)wordbase[f >> 5] +
             __popc(bitmap[f >> 5] & ((1u << (f & 31)) - 1u));

  const uint64_t vball = __ballot(valid);
  const int DBs = 128 * (int)__popcll(vball & 0xffffffffull);
  const int DBn = 128 * (int)__popcll(vball >> 32);

  uint32_t accs[8], accn[8];
#pragma unroll
  for (int k = 0; k < 8; ++k) { accs[k] = 0u; accn[k] = 0u; }

  // prefetch chunk 0: wave w stages ranks w*4 .. w*4+3
  uint4 pf[4];
#pragma unroll
  for (int u = 0; u < 4; ++u) {
    int rk = w * 4 + u;
    if (rk < su) {
      int ff = ulist[rk];
      pf[u] = ((const uint4*)(wQ + (size_t)ff * HIDDEN))[lane];
    }
  }

  for (int c = 0; c < nchunks; ++c) {
    // commit staged columns for chunk c
#pragma unroll
    for (int u = 0; u < 4; ++u) {
      int rk = c * CHUNK + w * 4 + u;
      if (rk < su) buf[(w * 4 + u) * 64 + lane] = pf[u];
    }
    __syncthreads();
    // prefetch chunk c+1 (global latency overlaps LDS consume below)
#pragma unroll
    for (int u = 0; u < 4; ++u) {
      int rk = (c + 1) * CHUNK + w * 4 + u;
      if (rk < su) {
        int ff = ulist[rk];
        pf[u] = ((const uint4*)(wQ + (size_t)ff * HIDDEN))[lane];
      }
    }
    // consume: walk this wave's instances whose rank falls in chunk c
    uint64_t inm = __ballot(valid && (unsigned)(r_lane - c * CHUNK) < CHUNK);
    uint32_t ms = (uint32_t)inm, mn = (uint32_t)(inm >> 32);
    while (ms) {
      int j = __builtin_ctz(ms); ms &= ms - 1u;
      int slot = __builtin_amdgcn_readlane(r_lane, j) - c * CHUNK;
      acc16(accs, buf[slot * 64 + lane]);
    }
    while (mn) {
      int j = __builtin_ctz(mn); mn &= mn - 1u;
      int slot = __builtin_amdgcn_readlane(r_lane, 32 + j) - c * CHUNK;
      acc16(accn, buf[slot * 64 + lane]);
    }
    __syncthreads();
  }

  // Epilogue: dequant + bias + clip01, fused 2048-dot with out_w, sigmoid.
  const int hbase = lane * 16;
  const float4* s4 = (const float4*)(scale + hbase);
  const float4* b4 = (const float4*)(bias + hbase);
  const float4* oS = (const float4*)(outw + hbase);
  const float4* oN = (const float4*)(outw + HIDDEN + hbase);
  float partial = 0.f;
#pragma unroll
  for (int q = 0; q < 4; ++q) {
    float4 sv = s4[q], bv = b4[q], ov = oS[q], nv = oN[q];
    const float* sp = &sv.x; const float* bp = &bv.x;
    const float* op = &ov.x; const float* np = &nv.x;
#pragma unroll
    for (int e = 0; e < 4; ++e) {
      int k = q * 4 + e;
      uint32_t as = accs[k >> 1], an = accn[k >> 1];
      int qs = (int)((k & 1) ? (as >> 16) : (as & 0xffffu)) - DBs;
      int qn = (int)((k & 1) ? (an >> 16) : (an & 0xffffu)) - DBn;
      float hs = fminf(fmaxf(fmaf((float)qs, sp[e], bp[e]), 0.f), 1.f);
      float hn = fminf(fmaxf(fmaf((float)qn, sp[e], bp[e]), 0.f), 1.f);
      partial += hs * op[e] + hn * np[e];
    }
  }
#pragma unroll
  for (int off = 32; off > 0; off >>= 1)
    partial += __shfl_down(partial, off, 64);
  if (lane == 0) {
    float y = partial + outb[0];
    out[row] = 1.f / (1.f + __expf(-y));
  }
}

extern "C" void kernel_launch(void* const* d_in, const int* in_sizes, int n_in,
                              void* d_out, int out_size, void* d_ws, size_t ws_size,
                              hipStream_t stream) {
  const int*   stm  = (const int*)d_in[0];
  const int*   nstm = (const int*)d_in[1];
  const float* ftw  = (const float*)d_in[2];   // (1024, 768) fp32
  const float* ftb  = (const float*)d_in[3];   // (1024,) fp32
  const float* outw = (const float*)d_in[4];   // (2048,) fp32
  const float* outb = (const float*)d_in[5];   // (1,) fp32

  uint8_t* wQ    = (uint8_t*)d_ws;                         // 768 KB
  float*   scale = (float*)(wQ + (size_t)FEAT * HIDDEN);   // 4 KB
  float*   invsc = scale + HIDDEN;                         // 4 KB

  scale_k<<<HIDDEN, 256, 0, stream>>>(ftw, scale, invsc);
  tilequant<<<(FEAT / 64) * (HIDDEN / 64), 256, 0, stream>>>(ftw, invsc, wQ);
  nn_fwd<<<BATCH / RPB, 1024, 0, stream>>>(stm, nstm, wQ, scale, ftb, outw,
                                           outb, (float*)d_out);
}

// Round 8
// 174.569 us; speedup vs baseline: 1.5213x; 1.5213x over previous
//
#include <hip/hip_runtime.h>
#include <hip/hip_bf16.h>
#include <stdint.h>

#define BATCH 16384
#define MAXA 32
#define FEAT 768
#define HIDDEN 1024
#define RPB 16          // rows per block (= waves per block)
#define CHUNK 32        // staged columns per chunk (32 KB LDS buffer)

// ---------------------------------------------------------------------------
// Prep (merged): per-h absmax -> scale, then quantize + transpose.
// Block b owns h-slab [b*64, b*64+64); 256 threads; 16 blocks.
// wQ[f][h] biased u8 (q+128), 1 KB per feature column.
// ---------------------------------------------------------------------------
__global__ __launch_bounds__(256) void prep(const float* __restrict__ ftw,
                                            uint8_t* __restrict__ wQ,
                                            float* __restrict__ scale) {
  const int h0   = blockIdx.x * 64;
  const int lane = threadIdx.x & 63;
  const int w4   = threadIdx.x >> 6;      // 0..3
  __shared__ float s_inv[64];

  // per-h absmax over f (wave per row, coalesced)
  for (int g = 0; g < 16; ++g) {
    const int hh = g * 4 + w4;
    const float* rp = ftw + (size_t)(h0 + hh) * FEAT;
    float a = 0.f;
#pragma unroll
    for (int it = 0; it < 12; ++it) a = fmaxf(a, fabsf(rp[lane + it * 64]));
#pragma unroll
    for (int off = 32; off > 0; off >>= 1)
      a = fmaxf(a, __shfl_xor(a, off, 64));
    if (lane == 0) {
      a = fmaxf(a, 1e-20f);
      scale[h0 + hh] = a / 127.f;
      s_inv[hh] = 127.f / a;
    }
  }
  __syncthreads();

  // quantize + transpose, 12 tiles of 64f x 64h
  __shared__ uint8_t tile[64][80];        // 80: 16B-aligned rows
  for (int t = 0; t < 12; ++t) {
    const int f0 = t * 64;
#pragma unroll
    for (int p = 0; p < 16; ++p) {
      int hh = p * 4 + w4;
      float v = ftw[(size_t)(h0 + hh) * FEAT + f0 + lane];
      int q = __float2int_rn(v * s_inv[hh]);   // [-127,127]
      tile[lane][hh] = (uint8_t)(q + 128);
    }
    __syncthreads();
    const int fs = threadIdx.x >> 2, part = threadIdx.x & 3;
    *(uint4*)(wQ + (size_t)(f0 + fs) * HIDDEN + h0 + part * 16) =
        *(const uint4*)&tile[fs][part * 16];
    __syncthreads();
  }
}

// packed u16 accumulate: plain u32 add == 2xu16 add (field max 32*255 = 8160).
__device__ __forceinline__ void acc16(uint32_t* acc, uint4 w) {
  acc[0] += __builtin_amdgcn_perm(0u, w.x, 0x0c010c00u);
  acc[1] += __builtin_amdgcn_perm(0u, w.x, 0x0c030c02u);
  acc[2] += __builtin_amdgcn_perm(0u, w.y, 0x0c010c00u);
  acc[3] += __builtin_amdgcn_perm(0u, w.y, 0x0c030c02u);
  acc[4] += __builtin_amdgcn_perm(0u, w.z, 0x0c010c00u);
  acc[5] += __builtin_amdgcn_perm(0u, w.z, 0x0c030c02u);
  acc[6] += __builtin_amdgcn_perm(0u, w.w, 0x0c010c00u);
  acc[7] += __builtin_amdgcn_perm(0u, w.w, 0x0c030c02u);
}

// 16 rows per 1024-thread block. Block-unique feature staging through LDS.
// Pipeline is the R6-validated ordering (commit; barrier; prefetch-issue;
// consume; barrier) — provably race-free — with CHUNK=32 / 2-column prefetch
// so register state fits without spill (R6's failure was scratch spill).
__global__ __launch_bounds__(1024, 4) void nn_fwd(
    const int* __restrict__ stm, const int* __restrict__ nstm,
    const uint8_t* __restrict__ wQ, const float* __restrict__ scale,
    const float* __restrict__ bias, const float* __restrict__ outw,
    const float* __restrict__ outb, float* __restrict__ out)
{
  const int tid  = threadIdx.x;
  const int lane = tid & 63;
  const int w    = tid >> 6;                  // wave id = local row
  const int row  = blockIdx.x * RPB + w;
  const int half = lane >> 5;                 // 0 = stm, 1 = nstm
  const int pos  = lane & 31;

  __shared__ uint32_t bitmap[24];             // 768-bit presence
  __shared__ uint32_t wordbase[24];           // exclusive popcount prefix
  __shared__ int      s_unique;
  __shared__ uint16_t ulist[FEAT];            // sorted unique feature ids
  __shared__ uint4    buf[CHUNK * 64];        // 32 KB column staging

  if (tid < 24) bitmap[tid] = 0u;
  __syncthreads();

  const int* __restrict__ src = half ? nstm : stm;
  int f = src[row * MAXA + pos];
  bool valid = f >= 0;
  // per-side dedupe: reference .at[].max() counts duplicates once
#pragma unroll
  for (int j = 0; j < 31; ++j) {
    int other = __shfl(f, (half << 5) | j, 64);
    if (j < pos && other == f) valid = false;
  }
  if (valid) atomicOr((unsigned int*)&bitmap[f >> 5], 1u << (f & 31));
  __syncthreads();

  // wave 0: prefix-sum word popcounts, emit sorted unique list
  if (tid < 64) {
    uint32_t wv = (tid < 24) ? bitmap[tid] : 0u;
    int cnt = __popc(wv);
    int inc = cnt;
#pragma unroll
    for (int off = 1; off < 32; off <<= 1) {
      int t = __shfl_up(inc, off, 64);
      if (lane >= off) inc += t;
    }
    if (tid < 24) {
      int excl = inc - cnt;
      wordbase[tid] = (uint32_t)excl;
      int r = excl; uint32_t wt = wv;
      while (wt) { int b = __builtin_ctz(wt); wt &= wt - 1u;
                   ulist[r++] = (uint16_t)(tid * 32 + b); }
      if (tid == 23) s_unique = inc;
    }
  }
  __syncthreads();

  const int su = s_unique;
  const int nchunks = (su + CHUNK - 1) / CHUNK;   // uniform across block

  // rank of this lane's feature in the sorted unique list
  int r_lane = 0x7FFFFFFF;
  if (valid)
    r_lane = (int)wordbase[f >> 5] +
             __popc(bitmap[f >> 5] & ((1u << (f & 31)) - 1u));

  const uint64_t vball = __ballot(valid);
  const int DBs = 128 * (int)__popcll(vball & 0xffffffffull);
  const int DBn = 128 * (int)__popcll(vball >> 32);

  uint32_t accs[8], accn[8];
#pragma unroll
  for (int k = 0; k < 8; ++k) { accs[k] = 0u; accn[k] = 0u; }

  // prefetch chunk 0 into registers (wave w owns chunk-slots w*2, w*2+1)
  uint4 pf0, pf1;
  bool g0 = false, g1 = false;
  {
    int rk0 = w * 2, rk1 = w * 2 + 1;
    if (rk0 < su) { pf0 = ((const uint4*)(wQ + (size_t)ulist[rk0] * HIDDEN))[lane]; g0 = true; }
    if (rk1 < su) { pf1 = ((const uint4*)(wQ + (size_t)ulist[rk1] * HIDDEN))[lane]; g1 = true; }
  }

  for (int c = 0; c < nchunks; ++c) {
    // commit prefetched columns for chunk c
    if (g0) buf[(w * 2) * 64 + lane] = pf0;
    if (g1) buf[(w * 2 + 1) * 64 + lane] = pf1;
    __syncthreads();                       // staging visible to all waves
    // issue prefetch for chunk c+1 (global latency overlaps LDS consume)
    g0 = g1 = false;
    {
      int rk0 = (c + 1) * CHUNK + w * 2, rk1 = rk0 + 1;
      if (rk0 < su) { pf0 = ((const uint4*)(wQ + (size_t)ulist[rk0] * HIDDEN))[lane]; g0 = true; }
      if (rk1 < su) { pf1 = ((const uint4*)(wQ + (size_t)ulist[rk1] * HIDDEN))[lane]; g1 = true; }
    }
    // consume chunk c from LDS
    uint64_t inm = __ballot(valid && (unsigned)(r_lane - c * CHUNK) < CHUNK);
    uint32_t ms = (uint32_t)inm, mn = (uint32_t)(inm >> 32);
    while (ms) {
      int j = __builtin_ctz(ms); ms &= ms - 1u;
      int slot = __builtin_amdgcn_readlane(r_lane, j) - c * CHUNK;
      acc16(accs, buf[slot * 64 + lane]);
    }
    while (mn) {
      int j = __builtin_ctz(mn); mn &= mn - 1u;
      int slot = __builtin_amdgcn_readlane(r_lane, 32 + j) - c * CHUNK;
      acc16(accn, buf[slot * 64 + lane]);
    }
    __syncthreads();                       // all reads done before next commit
  }

  // Epilogue: dequant + bias + clip01, fused 2048-dot with out_w, sigmoid.
  const int hbase = lane * 16;
  const float4* s4 = (const float4*)(scale + hbase);
  const float4* b4 = (const float4*)(bias + hbase);
  const float4* oS = (const float4*)(outw + hbase);
  const float4* oN = (const float4*)(outw + HIDDEN + hbase);
  float partial = 0.f;
#pragma unroll
  for (int q = 0; q < 4; ++q) {
    float4 sv = s4[q], bv = b4[q], ov = oS[q], nv = oN[q];
    const float* sp = &sv.x; const float* bp = &bv.x;
    const float* op = &ov.x; const float* np = &nv.x;
#pragma unroll
    for (int e = 0; e < 4; ++e) {
      int k = q * 4 + e;
      uint32_t as = accs[k >> 1], an = accn[k >> 1];
      int qs = (int)((k & 1) ? (as >> 16) : (as & 0xffffu)) - DBs;
      int qn = (int)((k & 1) ? (an >> 16) : (an & 0xffffu)) - DBn;
      float hs = fminf(fmaxf(fmaf((float)qs, sp[e], bp[e]), 0.f), 1.f);
      float hn = fminf(fmaxf(fmaf((float)qn, sp[e], bp[e]), 0.f), 1.f);
      partial += hs * op[e] + hn * np[e];
    }
  }
#pragma unroll
  for (int off = 32; off > 0; off >>= 1)
    partial += __shfl_down(partial, off, 64);
  if (lane == 0) {
    float y = partial + outb[0];
    out[row] = 1.f / (1.f + __expf(-y));
  }
}

extern "C" void kernel_launch(void* const* d_in, const int* in_sizes, int n_in,
                              void* d_out, int out_size, void* d_ws, size_t ws_size,
                              hipStream_t stream) {
  const int*   stm  = (const int*)d_in[0];
  const int*   nstm = (const int*)d_in[1];
  const float* ftw  = (const float*)d_in[2];   // (1024, 768) fp32
  const float* ftb  = (const float*)d_in[3];   // (1024,) fp32
  const float* outw = (const float*)d_in[4];   // (2048,) fp32
  const float* outb = (const float*)d_in[5];   // (1,) fp32

  uint8_t* wQ    = (uint8_t*)d_ws;                         // 768 KB
  float*   scale = (float*)(wQ + (size_t)FEAT * HIDDEN);   // 4 KB

  prep<<<HIDDEN / 64, 256, 0, stream>>>(ftw, wQ, scale);
  nn_fwd<<<BATCH / RPB, 1024, 0, stream>>>(stm, nstm, wQ, scale, ftb, outw,
                                           outb, (float*)d_out);
}

// Round 9
// 123.098 us; speedup vs baseline: 2.1574x; 1.4181x over previous
//
#include <hip/hip_runtime.h>
#include <hip/hip_bf16.h>
#include <stdint.h>

#define BATCH 16384
#define MAXA 32
#define FEAT 768
#define HIDDEN 1024
// replica stride: 768 feature columns + 1 dummy zero column, 1 KB each
#define REPSTRIDE ((size_t)(FEAT + 1) * HIDDEN)

// ---------------------------------------------------------------------------
// Prep 1: per-hidden-column max -> scale/invscale; block 1024 inits the dummy
// zero column (q=0 biased -> byte 128) in EVERY replica.
// ---------------------------------------------------------------------------
__global__ __launch_bounds__(256) void scale_k(const float* __restrict__ ftw,
                                               float* __restrict__ scale,
                                               float* __restrict__ invsc,
                                               uint8_t* __restrict__ wQ,
                                               int nrep) {
  if (blockIdx.x == HIDDEN) {
    if (threadIdx.x < 64) {
      uint4 v; v.x = v.y = v.z = v.w = 0x80808080u;
      for (int r = 0; r < nrep; ++r)
        ((uint4*)(wQ + r * REPSTRIDE + (size_t)FEAT * HIDDEN))[threadIdx.x] = v;
    }
    return;
  }
  const int h = blockIdx.x;
  float a = 0.f;
#pragma unroll
  for (int p = 0; p < 3; ++p)
    a = fmaxf(a, fabsf(ftw[h * FEAT + p * 256 + threadIdx.x]));
#pragma unroll
  for (int off = 32; off > 0; off >>= 1)
    a = fmaxf(a, __shfl_xor(a, off, 64));
  __shared__ float red[4];
  if ((threadIdx.x & 63) == 0) red[threadIdx.x >> 6] = a;
  __syncthreads();
  if (threadIdx.x == 0) {
    float m = fmaxf(fmaxf(red[0], red[1]), fmaxf(red[2], red[3]));
    m = fmaxf(m, 1e-20f);
    scale[h] = m / 127.f;
    invsc[h] = 127.f / m;
  }
}

// ---------------------------------------------------------------------------
// Prep 2: quantize + transpose, LDS-tiled, coalesced reads + 16 B stores,
// replicated nrep times (one copy per XCD so gathers stay XCD-local).
// ---------------------------------------------------------------------------
__global__ __launch_bounds__(256) void tilequant(const float* __restrict__ ftw,
                                                 const float* __restrict__ invsc,
                                                 uint8_t* __restrict__ wQ,
                                                 int nrep) {
  const int f0 = (blockIdx.x % (FEAT / 64)) * 64;
  const int h0 = (blockIdx.x / (FEAT / 64)) * 64;
  __shared__ uint8_t tile[64][80];
  __shared__ float inv[64];
  if (threadIdx.x < 64) inv[threadIdx.x] = invsc[h0 + threadIdx.x];
  __syncthreads();
  const int ff = threadIdx.x & 63;
  const int hb = threadIdx.x >> 6;
#pragma unroll
  for (int p = 0; p < 16; ++p) {
    int hh = p * 4 + hb;
    float w = ftw[(size_t)(h0 + hh) * FEAT + f0 + ff];
    int q = __float2int_rn(w * inv[hh]);
    tile[ff][hh] = (uint8_t)(q + 128);
  }
  __syncthreads();
  const int fs = threadIdx.x >> 2, part = threadIdx.x & 3;
  uint4 v = *(const uint4*)&tile[fs][part * 16];
  size_t off = (size_t)(f0 + fs) * HIDDEN + h0 + part * 16;
  for (int r = 0; r < nrep; ++r)
    *(uint4*)(wQ + r * REPSTRIDE + off) = v;
}

// packed u16 accumulate: plain u32 add == 2xu16 add (field max 32*255 = 8160).
__device__ __forceinline__ void acc16(uint32_t* acc, uint4 w) {
  acc[0] += __builtin_amdgcn_perm(0u, w.x, 0x0c010c00u);
  acc[1] += __builtin_amdgcn_perm(0u, w.x, 0x0c030c02u);
  acc[2] += __builtin_amdgcn_perm(0u, w.y, 0x0c010c00u);
  acc[3] += __builtin_amdgcn_perm(0u, w.y, 0x0c030c02u);
  acc[4] += __builtin_amdgcn_perm(0u, w.z, 0x0c010c00u);
  acc[5] += __builtin_amdgcn_perm(0u, w.z, 0x0c030c02u);
  acc[6] += __builtin_amdgcn_perm(0u, w.w, 0x0c010c00u);
  acc[7] += __builtin_amdgcn_perm(0u, w.w, 0x0c030c02u);
}

// One wave per batch row (R4-proven structure). Lane L owns h = L*16..+15 for
// both sides. Branch-free: invalid/dup features -> dummy zero column f=768.
// NEW: each wave reads the weight replica on ITS OWN XCD (HW_REG_XCC_ID),
// so all column gathers are XCD-local L2 hits instead of cross-die fabric.
__global__ __launch_bounds__(256, 6) void nn_fwd(
    const int* __restrict__ stm, const int* __restrict__ nstm,
    const uint8_t* __restrict__ wQ, const float* __restrict__ scale,
    const float* __restrict__ bias, const float* __restrict__ outw,
    const float* __restrict__ outb, float* __restrict__ out, int repmask)
{
  const int lane = threadIdx.x & 63;
  const int row  = blockIdx.x * 4 + (threadIdx.x >> 6);
  const int half = lane >> 5;       // 0 = stm, 1 = nstm
  const int pos  = lane & 31;

  uint32_t xcc;
  asm("s_getreg_b32 %0, hwreg(HW_REG_XCC_ID)" : "=s"(xcc));
  const uint8_t* __restrict__ wx = wQ + (size_t)(xcc & (uint32_t)repmask) * REPSTRIDE;

  const int* __restrict__ src = half ? nstm : stm;
  int idx = src[row * MAXA + pos];
  bool valid = idx >= 0;            // -1 padding -> no contribution
  // dedupe within each half: reference .at[].max() counts duplicates once
#pragma unroll
  for (int j = 0; j < 31; ++j) {
    int other = __shfl(idx, (half << 5) | j, 64);
    if (j < pos && other == idx) valid = false;
  }
  const int fmap = valid ? idx : FEAT;   // dummy zero column

  uint32_t accs[8], accn[8];
#pragma unroll
  for (int k = 0; k < 8; ++k) { accs[k] = 0u; accn[k] = 0u; }

  // 8 groups x (8 scalar-based loads then 8 accs), ~8 KB in flight per wave
#pragma unroll
  for (int jb = 0; jb < 32; jb += 4) {
    uint4 ws[4], wn[4];
#pragma unroll
    for (int u = 0; u < 4; ++u) {
      int fs_ = __builtin_amdgcn_readlane(fmap, jb + u);
      int fn_ = __builtin_amdgcn_readlane(fmap, 32 + jb + u);
      ws[u] = ((const uint4*)(wx + (size_t)fs_ * HIDDEN))[lane];
      wn[u] = ((const uint4*)(wx + (size_t)fn_ * HIDDEN))[lane];
    }
#pragma unroll
    for (int u = 0; u < 4; ++u) { acc16(accs, ws[u]); acc16(accn, wn[u]); }
  }

  const int DB = 32 * 128;   // constant de-bias (every slot contributes +128)

  // Epilogue: dequant + bias + clip01, fused 2048-dot with out_w, sigmoid.
  const int hbase = lane * 16;
  const float4* s4 = (const float4*)(scale + hbase);
  const float4* b4 = (const float4*)(bias + hbase);
  const float4* oS = (const float4*)(outw + hbase);
  const float4* oN = (const float4*)(outw + HIDDEN + hbase);
  float partial = 0.f;
#pragma unroll
  for (int q = 0; q < 4; ++q) {
    float4 sv = s4[q], bv = b4[q], ov = oS[q], nv = oN[q];
    const float* sp = &sv.x; const float* bp = &bv.x;
    const float* op = &ov.x; const float* np = &nv.x;
#pragma unroll
    for (int e = 0; e < 4; ++e) {
      int k = q * 4 + e;
      uint32_t as = accs[k >> 1], an = accn[k >> 1];
      int qs = (int)((k & 1) ? (as >> 16) : (as & 0xffffu)) - DB;
      int qn = (int)((k & 1) ? (an >> 16) : (an & 0xffffu)) - DB;
      float hs = fminf(fmaxf(fmaf((float)qs, sp[e], bp[e]), 0.f), 1.f);
      float hn = fminf(fmaxf(fmaf((float)qn, sp[e], bp[e]), 0.f), 1.f);
      partial += hs * op[e] + hn * np[e];
    }
  }
#pragma unroll
  for (int off = 32; off > 0; off >>= 1)
    partial += __shfl_down(partial, off, 64);
  if (lane == 0) {
    float y = partial + outb[0];
    out[row] = 1.f / (1.f + __expf(-y));
  }
}

extern "C" void kernel_launch(void* const* d_in, const int* in_sizes, int n_in,
                              void* d_out, int out_size, void* d_ws, size_t ws_size,
                              hipStream_t stream) {
  const int*   stm  = (const int*)d_in[0];
  const int*   nstm = (const int*)d_in[1];
  const float* ftw  = (const float*)d_in[2];   // (1024, 768) fp32
  const float* ftb  = (const float*)d_in[3];   // (1024,) fp32
  const float* outw = (const float*)d_in[4];   // (2048,) fp32
  const float* outb = (const float*)d_in[5];   // (1,) fp32

  // replicas: one per XCD if the workspace allows (power of 2 for masking)
  int nrep = 1;
  while (nrep < 8 &&
         (size_t)(nrep * 2) * REPSTRIDE + 2 * HIDDEN * sizeof(float) <= ws_size)
    nrep *= 2;

  uint8_t* wQ    = (uint8_t*)d_ws;                          // nrep * 769 KB
  float*   scale = (float*)(wQ + (size_t)nrep * REPSTRIDE); // 4 KB
  float*   invsc = scale + HIDDEN;                          // 4 KB

  scale_k<<<HIDDEN + 1, 256, 0, stream>>>(ftw, scale, invsc, wQ, nrep);
  tilequant<<<(FEAT / 64) * (HIDDEN / 64), 256, 0, stream>>>(ftw, invsc, wQ, nrep);
  nn_fwd<<<BATCH / 4, 256, 0, stream>>>(stm, nstm, wQ, scale, ftb, outw, outb,
                                        (float*)d_out, nrep - 1);
}